// Round 2
// baseline (767.876 us; speedup 1.0000x reference)
//
#include <hip/hip_runtime.h>
#include <stdint.h>

#define PRIME 2147483647LL
#define NUM_EMB 100000
#define NUM_BUCKETS 65536
#define EMB 64
#define N_ARY 32
#define NDIG 16
#define CAP 16   // slot capacity per bucket; overflow list handles the rest

struct HashConsts {
  long long seqA[NDIG];
  long long hashA[2];
  long long hashB[2];
};

// ---------------- zero init: ws metadata region + output ----------------
__global__ __launch_bounds__(256) void zero_kernel(uint4* __restrict__ wsv, int n_ws,
                                                   uint4* __restrict__ outv, int n_out) {
  int i = blockIdx.x * blockDim.x + threadIdx.x;
  int stride = gridDim.x * blockDim.x;
  uint4 z = make_uint4(0u, 0u, 0u, 0u);
  for (int k = i; k < n_ws; k += stride) wsv[k] = z;
  for (int k = i; k < n_out; k += stride) outv[k] = z;
}

// ---------------- pass 1: hash + scatter uses into per-bucket lists ------
__global__ __launch_bounds__(256) void pass1_kernel(
    const int* __restrict__ seq, const float* __restrict__ iw, HashConsts hc,
    uint32_t* __restrict__ cnt, uint32_t* __restrict__ slots,
    float2* __restrict__ wpair, int2* __restrict__ ovf, uint32_t* __restrict__ ovfcnt,
    int npairs) {
  int tid = blockIdx.x * 256 + threadIdx.x;
  if (tid >= npairs) return;
  int b = tid >> 4, d = tid & 15;
  const int* srow = seq + b * NDIG;
  int vj[NDIG];
  int len = 0;
#pragma unroll
  for (int j = 0; j < NDIG; ++j) { vj[j] = srow[j]; len += (vj[j] != 0); }
  int idx = min(d, max(len - 1, 0));
  long long acc = 0;
#pragma unroll
  for (int j = 0; j < NDIG; ++j)
    if (j <= idx) acc += hc.seqA[j] * (long long)vj[j];
  long long id = acc % PRIME;
  int widx = (int)(id % NUM_EMB);
  wpair[tid] = make_float2(iw[widx * 2 + 0], iw[widx * 2 + 1]);
#pragma unroll
  for (int h = 0; h < 2; ++h) {
    unsigned int bk =
        (unsigned int)((hc.hashA[h] * id + hc.hashB[h]) % PRIME) & (NUM_BUCKETS - 1);
    uint32_t slot = atomicAdd(&cnt[bk], 1u);
    uint32_t entry = ((uint32_t)tid << 1) | (uint32_t)h;
    if (slot < CAP) slots[bk * CAP + slot] = entry;
    else {
      uint32_t o = atomicAdd(ovfcnt, 1u);
      ovf[o] = make_int2((int)entry, (int)bk);
    }
  }
}

// ---------------- pass 2: one block per bucket, row read once ------------
// thread t holds row floats [8t, 8t+8): a = t>>3 (0..31), eg = t&7 (e-octet)
__global__ __launch_bounds__(256) void gather_kernel(
    const float* __restrict__ bt, const float* __restrict__ rep,
    const uint32_t* __restrict__ cnt, const uint32_t* __restrict__ slots,
    const float2* __restrict__ wpair, float* __restrict__ out) {
  const int bkt = blockIdx.x;
  int n = (int)cnt[bkt];
  if (n == 0) return;
  if (n > CAP) n = CAP;
  const int t = threadIdx.x;
  const float4* rowp = (const float4*)(bt + (size_t)bkt * (N_ARY * EMB));
  float4 ra = rowp[t * 2 + 0];
  float4 rb = rowp[t * 2 + 1];
  const int a = t >> 3;
  const int eg = t & 7;
  for (int u = 0; u < n; ++u) {
    uint32_t s = slots[bkt * CAP + u];
    int pair = (int)(s >> 1);
    int h = (int)(s & 1u);
    float2 wp = wpair[pair];
    float w = h ? wp.y : wp.x;
    const float4* rp = (const float4*)(rep + (size_t)pair * EMB + eg * 8);
    float4 c0 = rp[0], c1 = rp[1];
    float p = ra.x * c0.x + ra.y * c0.y + ra.z * c0.z + ra.w * c0.w +
              rb.x * c1.x + rb.y * c1.y + rb.z * c1.z + rb.w * c1.w;
    p += __shfl_xor(p, 1, 64);
    p += __shfl_xor(p, 2, 64);
    p += __shfl_xor(p, 4, 64);
    if (eg == 0) atomicAdd(out + (size_t)pair * N_ARY + a, w * p);
  }
}

// ---------------- pass 3: overflow drain (normally zero entries) ---------
__global__ __launch_bounds__(256) void overflow_kernel(
    const float* __restrict__ bt, const float* __restrict__ rep,
    const int2* __restrict__ ovf, const uint32_t* __restrict__ ovfcnt,
    const float2* __restrict__ wpair, float* __restrict__ out) {
  const uint32_t n = *ovfcnt;
  const int t = threadIdx.x;
  const int a = t >> 3;
  const int eg = t & 7;
  for (uint32_t e = blockIdx.x; e < n; e += gridDim.x) {
    int2 en = ovf[e];
    int pair = en.x >> 1;
    int h = en.x & 1;
    int bkt = en.y;
    const float4* rowp = (const float4*)(bt + (size_t)bkt * (N_ARY * EMB));
    float4 ra = rowp[t * 2 + 0];
    float4 rb = rowp[t * 2 + 1];
    float2 wp = wpair[pair];
    float w = h ? wp.y : wp.x;
    const float4* rp = (const float4*)(rep + (size_t)pair * EMB + eg * 8);
    float4 c0 = rp[0], c1 = rp[1];
    float p = ra.x * c0.x + ra.y * c0.y + ra.z * c0.z + ra.w * c0.w +
              rb.x * c1.x + rb.y * c1.y + rb.z * c1.z + rb.w * c1.w;
    p += __shfl_xor(p, 1, 64);
    p += __shfl_xor(p, 2, 64);
    p += __shfl_xor(p, 4, 64);
    if (eg == 0) atomicAdd(out + (size_t)pair * N_ARY + a, w * p);
  }
}

// ---------------- fallback: round-1 monolithic kernel (ws too small) -----
__global__ __launch_bounds__(256) void hash_logits_kernel(
    const int* __restrict__ seq, const float* __restrict__ rep,
    const float* __restrict__ iw, const float* __restrict__ bt,
    float* __restrict__ out, HashConsts hc) {
  const int bid = blockIdx.x;
  const int b = bid >> 2;
  const int wave = threadIdx.x >> 6;
  const int d = ((bid & 3) << 2) | wave;
  const int lane = threadIdx.x & 63;
  const int g = lane >> 4;
  const int sub = lane & 15;
  const int* srow = seq + b * NDIG;
  int v[NDIG];
  int len = 0;
#pragma unroll
  for (int j = 0; j < NDIG; ++j) { v[j] = srow[j]; len += (v[j] != 0); }
  int idx = min(d, max(len - 1, 0));
  long long acc = 0;
#pragma unroll
  for (int j = 0; j < NDIG; ++j)
    if (j <= idx) acc += hc.seqA[j] * (long long)v[j];
  const long long id = acc % PRIME;
  const int widx = (int)(id % NUM_EMB);
  const float w0 = iw[widx * 2 + 0];
  const float w1 = iw[widx * 2 + 1];
  const unsigned int bk0 =
      (unsigned int)((hc.hashA[0] * id + hc.hashB[0]) % PRIME) & (NUM_BUCKETS - 1);
  const unsigned int bk1 =
      (unsigned int)((hc.hashA[1] * id + hc.hashB[1]) % PRIME) & (NUM_BUCKETS - 1);
  const float4* row0 = (const float4*)(bt + (size_t)bk0 * (N_ARY * EMB));
  const float4* row1 = (const float4*)(bt + (size_t)bk1 * (N_ARY * EMB));
  const float4 r = *(const float4*)(rep + ((size_t)b * NDIG + d) * EMB + sub * 4);
  float s[8];
#pragma unroll
  for (int k = 0; k < 8; ++k) {
    float4 v0 = row0[lane + 64 * k];
    float4 v1 = row1[lane + 64 * k];
    float ex = w0 * v0.x + w1 * v1.x;
    float ey = w0 * v0.y + w1 * v1.y;
    float ez = w0 * v0.z + w1 * v1.z;
    float ew = w0 * v0.w + w1 * v1.w;
    s[k] = ex * r.x + ey * r.y + ez * r.z + ew * r.w;
  }
#pragma unroll
  for (int m = 1; m <= 8; m <<= 1) {
#pragma unroll
    for (int k = 0; k < 8; ++k) s[k] += __shfl_xor(s[k], m, 64);
  }
  if (sub == 0) {
    float* obase = out + ((size_t)b * NDIG + d) * N_ARY + g;
#pragma unroll
    for (int k = 0; k < 8; ++k) obase[4 * k] = s[k];
  }
}

extern "C" void kernel_launch(void* const* d_in, const int* in_sizes, int n_in,
                              void* d_out, int out_size, void* d_ws, size_t ws_size,
                              hipStream_t stream) {
  // ---- reproduce np.random.RandomState(42) module-level constants ----
  uint32_t mt[624];
  int mti;
  mt[0] = 42u;
  for (int i = 1; i < 624; ++i)
    mt[i] = 1812433253u * (mt[i - 1] ^ (mt[i - 1] >> 30)) + (uint32_t)i;
  mti = 624;
  auto next32 = [&]() -> uint32_t {
    if (mti >= 624) {
      for (int i = 0; i < 624; ++i) {
        uint32_t y = (mt[i] & 0x80000000u) | (mt[(i + 1) % 624] & 0x7fffffffu);
        uint32_t x = mt[(i + 397) % 624] ^ (y >> 1);
        if (y & 1u) x ^= 2567483615u;
        mt[i] = x;
      }
      mti = 0;
    }
    uint32_t y = mt[mti++];
    y ^= y >> 11;
    y ^= (y << 7) & 2636928640u;
    y ^= (y << 15) & 4022730752u;
    y ^= y >> 18;
    return y;
  };
  auto draw = [&](uint32_t rng_incl) -> uint32_t {
    uint32_t val;
    do { val = next32() & 0x7FFFFFFFu; } while (val > rng_incl);
    return val;
  };
  HashConsts hc;
  for (int i = 0; i < NDIG; ++i) hc.seqA[i] = 1LL + (long long)draw(2147483645u);
  for (int i = 0; i < 2; ++i) hc.hashA[i] = 1LL + (long long)draw(2147483645u);
  for (int i = 0; i < 2; ++i) hc.hashB[i] = (long long)draw(2147483646u);

  const int* seq = (const int*)d_in[0];
  const float* rep = (const float*)d_in[1];
  const float* iw = (const float*)d_in[2];
  const float* bt = (const float*)d_in[3];
  float* out = (float*)d_out;

  const int B = in_sizes[0] / NDIG;  // 4096
  const int npairs = B * NDIG;       // 65536

  // ---- workspace layout (bytes) ----
  const size_t off_cnt = 0;
  const size_t sz_cnt = (size_t)NUM_BUCKETS * 4;                  // 256 KB
  const size_t off_meta_end = sz_cnt + 16;                        // + ovfcnt pad
  const size_t off_ovf = off_meta_end;                            // int2[2*npairs]
  const size_t sz_ovf = (size_t)npairs * 2 * 8;                   // 1 MB
  const size_t off_wpair = off_ovf + sz_ovf;                      // float2[npairs]
  const size_t sz_wpair = (size_t)npairs * 8;                     // 512 KB
  const size_t off_slots = off_wpair + sz_wpair;                  // u32[NB*CAP]
  const size_t sz_slots = (size_t)NUM_BUCKETS * CAP * 4;          // 4 MB
  const size_t need = off_slots + sz_slots;                       // ~6.03 MB

  if (ws_size < need) {
    // fallback: monolithic kernel (no workspace needed)
    dim3 grid(B * 4), block(256);
    hipLaunchKernelGGL(hash_logits_kernel, grid, block, 0, stream,
                       seq, rep, iw, bt, out, hc);
    return;
  }

  char* ws = (char*)d_ws;
  uint32_t* cnt = (uint32_t*)(ws + off_cnt);
  uint32_t* ovfcnt = (uint32_t*)(ws + sz_cnt);
  int2* ovf = (int2*)(ws + off_ovf);
  float2* wpair = (float2*)(ws + off_wpair);
  uint32_t* slots = (uint32_t*)(ws + off_slots);

  // 1. zero cnt + ovfcnt ([0, off_meta_end)) and out
  int n_ws_vec = (int)(off_meta_end / 16);      // 16385 uint4
  int n_out_vec = out_size / 4;                 // float4 count (out_size % 4 == 0)
  hipLaunchKernelGGL(zero_kernel, dim3(1024), dim3(256), 0, stream,
                     (uint4*)ws, n_ws_vec, (uint4*)out, n_out_vec);

  // 2. hash + scatter
  hipLaunchKernelGGL(pass1_kernel, dim3((npairs + 255) / 256), dim3(256), 0, stream,
                     seq, iw, hc, cnt, slots, wpair, ovf, ovfcnt, npairs);

  // 3. gather: one block per bucket, in bucket order (streaming table sweep)
  hipLaunchKernelGGL(gather_kernel, dim3(NUM_BUCKETS), dim3(256), 0, stream,
                     bt, rep, cnt, slots, wpair, out);

  // 4. overflow drain (normally empty)
  hipLaunchKernelGGL(overflow_kernel, dim3(128), dim3(256), 0, stream,
                     bt, rep, ovf, ovfcnt, wpair, out);
}